// Round 1
// baseline (4076.117 us; speedup 1.0000x reference)
//
#include <hip/hip_runtime.h>

// LSTM decoder: B=4096, H=256, 4H=1024, O=128, T=200.
// Strategy: recurrence is independent per batch row -> persistent kernel,
// 128 blocks x 32 rows, all 200 steps in-block, bf16 MFMA (16x16x32),
// f32 h/c masters. Weights pre-packed into MFMA B-fragment order.

#define B_SZ 4096
#define H_SZ 256
#define G4   1024
#define O_SZ 128
#define T_SZ 200

typedef __bf16 b16x8 __attribute__((ext_vector_type(8)));
typedef float f32x4 __attribute__((ext_vector_type(4)));
typedef unsigned short u16x8 __attribute__((ext_vector_type(8)));

__device__ __forceinline__ unsigned short f2bf(float x){
  unsigned u = __builtin_bit_cast(unsigned, x);
  u += 0x7FFFu + ((u >> 16) & 1u);          // RNE
  return (unsigned short)(u >> 16);
}
__device__ __forceinline__ float bf2f(unsigned short h){
  unsigned u = ((unsigned)h) << 16;
  return __builtin_bit_cast(float, u);
}
__device__ __forceinline__ float fsig(float x){
  float t = __builtin_amdgcn_exp2f(-1.4426950408889634f * x);
  return __builtin_amdgcn_rcpf(1.0f + t);
}
__device__ __forceinline__ float ftanh(float x){
  x = fminf(fmaxf(x, -15.0f), 15.0f);
  float e = __builtin_amdgcn_exp2f(2.8853900817779268f * x);  // e^{2x}
  return (e - 1.0f) * __builtin_amdgcn_rcpf(e + 1.0f);
}
__device__ __forceinline__ f32x4 mfma16(b16x8 a, b16x8 b, f32x4 c){
  return __builtin_amdgcn_mfma_f32_16x16x32_bf16(a, b, c, 0, 0, 0);
}

// ---- setup: pack weights to fragment order, split C into bf16 hi/lo ----
// packed layout (16-row n-tiles): dst[((ntile*8 + kk)*64 + l)*8 + j]
//   = W[(ntile*16 + (l&15))*256 + kk*32 + (l>>4)*8 + j]
// -> per (ntile,kk) one wave reads a contiguous 1 KB block.
__global__ void lstm_setup(const float* __restrict__ Wih, const float* __restrict__ Whh,
                           const float* __restrict__ Wlin, const float* __restrict__ bih,
                           const float* __restrict__ bhh, const float* __restrict__ C,
                           unsigned short* __restrict__ pWih, unsigned short* __restrict__ pWhh,
                           unsigned short* __restrict__ pWlin, float* __restrict__ bias,
                           unsigned short* __restrict__ Chi, unsigned short* __restrict__ Clo)
{
  const int nW = G4 * H_SZ;       // 262144
  const int nL = O_SZ * H_SZ;     // 32768
  const int nC = B_SZ * H_SZ;     // 1048576
  long i = (long)blockIdx.x * blockDim.x + threadIdx.x;
  if (i < nW){
    int d = (int)i;
    int j = d & 7, l = (d >> 3) & 63, kk = (d >> 9) & 7, nt = d >> 12;
    int src = (nt * 16 + (l & 15)) * H_SZ + kk * 32 + (l >> 4) * 8 + j;
    pWih[d] = f2bf(Wih[src]);
    pWhh[d] = f2bf(Whh[src]);
  } else if (i < nW + nL){
    int d = (int)(i - nW);
    int j = d & 7, l = (d >> 3) & 63, kk = (d >> 9) & 7, nt = d >> 12;
    int src = (nt * 16 + (l & 15)) * H_SZ + kk * 32 + (l >> 4) * 8 + j;
    pWlin[d] = f2bf(Wlin[src]);
  } else if (i < nW + nL + G4){
    int d = (int)(i - nW - nL);
    bias[d] = bih[d] + bhh[d];
  } else if (i < nW + nL + G4 + nC){
    int d = (int)(i - nW - nL - G4);
    float c = C[d];
    unsigned short hi = f2bf(c);
    Chi[d] = hi;
    Clo[d] = f2bf(c - bf2f(hi));
  }
}

// h_lds: bf16 [32][256], row stride 512 B, XOR-swizzled: byte_in_row ^= (row&15)<<4
__device__ __forceinline__ b16x8 ldsA(const unsigned short* h_lds, int row, int kbyte){
  int off = row * 512 + (kbyte ^ ((row & 15) << 4));
  return *(const b16x8*)((const char*)h_lds + off);
}
__device__ __forceinline__ b16x8 ldB(const unsigned short* __restrict__ p, int ntile, int kk, int l){
  return *(const b16x8*)(p + (((ntile * 8 + kk) << 6) + l) * 8);
}

__launch_bounds__(512, 2)
__global__ void lstm_main(const unsigned short* __restrict__ pWih,
                          const unsigned short* __restrict__ pWhh,
                          const unsigned short* __restrict__ pWlin,
                          const float* __restrict__ bias,
                          const unsigned short* __restrict__ Chi,
                          const unsigned short* __restrict__ Clo,
                          const float* __restrict__ blin,
                          float* __restrict__ xp_ws,
                          float* __restrict__ out)
{
  __shared__ unsigned short h_lds[32 * 256];   // 16 KB, swizzled
  const int tid = threadIdx.x;
  const int w = tid >> 6, l = tid & 63;
  const int lm = l & 15, lg = l >> 4;
  const int B0 = blockIdx.x * 32;

  // acc[mt][gate][u]: wave w owns gate cols n = g*256 + w*32 + u*16 + lm
  f32x4 acc[2][4][2];
  const f32x4 zero4 = {0.f, 0.f, 0.f, 0.f};
  #pragma unroll
  for (int mt = 0; mt < 2; mt++)
    #pragma unroll
    for (int g = 0; g < 4; g++)
      #pragma unroll
      for (int u = 0; u < 2; u++) acc[mt][g][u] = zero4;

  // ---- prologue: x_proj = (Chi + Clo) @ W_ih^T + (b_ih + b_hh) ----
  for (int pass = 0; pass < 2; pass++){
    const unsigned short* Csrc = pass ? Clo : Chi;
    __syncthreads();
    {
      int r = tid >> 4, c0 = (tid & 15) * 16;
      const u16x8* src = (const u16x8*)(Csrc + (long)(B0 + r) * H_SZ + c0);
      u16x8 v0 = src[0], v1 = src[1];
      int base = r * 512, sw = (r & 15) << 4;
      *(u16x8*)((char*)h_lds + base + (((c0 * 2)     ) ^ sw)) = v0;
      *(u16x8*)((char*)h_lds + base + (((c0 * 2) + 16) ^ sw)) = v1;
    }
    __syncthreads();
    #pragma unroll
    for (int kk = 0; kk < 8; kk++){
      b16x8 a0 = ldsA(h_lds, lm,      kk * 64 + lg * 16);
      b16x8 a1 = ldsA(h_lds, lm + 16, kk * 64 + lg * 16);
      #pragma unroll
      for (int g = 0; g < 4; g++)
        #pragma unroll
        for (int u = 0; u < 2; u++){
          b16x8 b = ldB(pWih, g * 16 + w * 2 + u, kk, l);
          acc[0][g][u] = mfma16(a0, b, acc[0][g][u]);
          acc[1][g][u] = mfma16(a1, b, acc[1][g][u]);
        }
    }
  }
  // add bias, dump x_proj to workspace in accumulator layout
  #pragma unroll
  for (int g = 0; g < 4; g++)
    #pragma unroll
    for (int u = 0; u < 2; u++){
      float bv = bias[g * 256 + w * 32 + u * 16 + lm];
      #pragma unroll
      for (int mt = 0; mt < 2; mt++)
        #pragma unroll
        for (int r = 0; r < 4; r++) acc[mt][g][u][r] += bv;
    }
  {
    f32x4* dst = (f32x4*)xp_ws;
    long base = ((long)blockIdx.x * 8 + w) * 1024;
    #pragma unroll
    for (int mt = 0; mt < 2; mt++)
      #pragma unroll
      for (int g = 0; g < 4; g++)
        #pragma unroll
        for (int u = 0; u < 2; u++){
          int fi = (mt * 4 + g) * 2 + u;
          dst[base + fi * 64 + l] = acc[mt][g][u];
        }
  }

  // ---- init h=0 (LDS), c=0 (regs) ----
  __syncthreads();
  {
    u16x8 z = {0,0,0,0,0,0,0,0};
    u16x8* p = (u16x8*)h_lds;
    p[tid * 2] = z; p[tid * 2 + 1] = z;
  }
  float cst[2][2][4];
  #pragma unroll
  for (int mt = 0; mt < 2; mt++)
    #pragma unroll
    for (int u = 0; u < 2; u++)
      #pragma unroll
      for (int r = 0; r < 4; r++) cst[mt][u][r] = 0.f;
  float bl = blin[w * 16 + lm];
  const f32x4* xps = (const f32x4*)xp_ws + ((long)blockIdx.x * 8 + w) * 1024 + l;
  __syncthreads();

  // ---- 200 recurrent steps ----
  for (int t = 0; t < T_SZ; t++){
    // gates = x_proj + h @ W_hh^T
    #pragma unroll
    for (int mt = 0; mt < 2; mt++)
      #pragma unroll
      for (int g = 0; g < 4; g++)
        #pragma unroll
        for (int u = 0; u < 2; u++)
          acc[mt][g][u] = xps[((mt * 4 + g) * 2 + u) * 64];
    #pragma unroll
    for (int kk = 0; kk < 8; kk++){
      b16x8 a0 = ldsA(h_lds, lm,      kk * 64 + lg * 16);
      b16x8 a1 = ldsA(h_lds, lm + 16, kk * 64 + lg * 16);
      #pragma unroll
      for (int g = 0; g < 4; g++)
        #pragma unroll
        for (int u = 0; u < 2; u++){
          b16x8 b = ldB(pWhh, g * 16 + w * 2 + u, kk, l);
          acc[0][g][u] = mfma16(a0, b, acc[0][g][u]);
          acc[1][g][u] = mfma16(a1, b, acc[1][g][u]);
        }
    }
    __syncthreads();   // all reads of h_{t-1} complete
    // elementwise LSTM cell; write h_t (bf16, swizzled) to LDS
    #pragma unroll
    for (int mt = 0; mt < 2; mt++)
      #pragma unroll
      for (int u = 0; u < 2; u++)
        #pragma unroll
        for (int r = 0; r < 4; r++){
          float iv = fsig (acc[mt][0][u][r]);
          float fv = fsig (acc[mt][1][u][r]);
          float gv = ftanh(acc[mt][2][u][r]);
          float ov = fsig (acc[mt][3][u][r]);
          float cn = fv * cst[mt][u][r] + iv * gv;
          cst[mt][u][r] = cn;
          float hv = ov * ftanh(cn);
          int row = mt * 16 + lg * 4 + r;
          int col = w * 32 + u * 16 + lm;
          *(unsigned short*)((char*)h_lds + row * 512 + ((col * 2) ^ ((row & 15) << 4))) = f2bf(hv);
        }
    __syncthreads();   // h_t visible
    // y = h_t @ W_lin^T + b_lin ; wave w owns output cols w*16+lm
    f32x4 ya0 = zero4, ya1 = zero4;
    #pragma unroll
    for (int kk = 0; kk < 8; kk++){
      b16x8 a0 = ldsA(h_lds, lm,      kk * 64 + lg * 16);
      b16x8 a1 = ldsA(h_lds, lm + 16, kk * 64 + lg * 16);
      b16x8 bb = ldB(pWlin, w, kk, l);
      ya0 = mfma16(a0, bb, ya0);
      ya1 = mfma16(a1, bb, ya1);
    }
    float* op = out + (long)t * (B_SZ * O_SZ) + (long)B0 * O_SZ + w * 16 + lm;
    #pragma unroll
    for (int r = 0; r < 4; r++){
      op[(lg * 4 + r) * O_SZ]        = ya0[r] + bl;
      op[(16 + lg * 4 + r) * O_SZ]   = ya1[r] + bl;
    }
  }
}

extern "C" void kernel_launch(void* const* d_in, const int* in_sizes, int n_in,
                              void* d_out, int out_size, void* d_ws, size_t ws_size,
                              hipStream_t stream)
{
  const float* C    = (const float*)d_in[0];
  // d_in[1] = t, d_in[2] = mask: unused by the reference
  const float* Wih  = (const float*)d_in[3];
  const float* Whh  = (const float*)d_in[4];
  const float* bih  = (const float*)d_in[5];
  const float* bhh  = (const float*)d_in[6];
  const float* Wlin = (const float*)d_in[7];
  const float* blin = (const float*)d_in[8];
  float* out = (float*)d_out;

  char* ws = (char*)d_ws;
  unsigned short* pWih = (unsigned short*)(ws);                 // 512 KB
  unsigned short* pWhh = (unsigned short*)(ws + 524288);        // 512 KB
  unsigned short* pWlin= (unsigned short*)(ws + 1048576);       // 64 KB
  float*          bias = (float*)(ws + 1114112);                // 4 KB
  unsigned short* Chi  = (unsigned short*)(ws + 1118208);       // 2 MB
  unsigned short* Clo  = (unsigned short*)(ws + 3215360);       // 2 MB
  float*          xp   = (float*)(ws + 5312512);                // 16 MB

  int total = 262144 + 32768 + 1024 + 1048576;
  lstm_setup<<<dim3((total + 255) / 256), dim3(256), 0, stream>>>(
      Wih, Whh, Wlin, bih, bhh, C, pWih, pWhh, pWlin, bias, Chi, Clo);
  lstm_main<<<dim3(128), dim3(512), 0, stream>>>(
      pWih, pWhh, pWlin, bias, Chi, Clo, blin, xp, out);
}